// Round 1
// baseline (444.334 us; speedup 1.0000x reference)
//
#include <hip/hip_runtime.h>
#include <stdint.h>
#include <stddef.h>

// Problem geometry (B=4, S=2048, DIN=4096, DOUT=4096)
constexpr int MDIM = 8192;   // B*S
constexpr int NDIM = 4096;   // DOUT
constexpr int KDIM = 4096;   // DIN
constexpr int TILE = 128;
constexpr int BK   = 64;

using f32x4 = __attribute__((ext_vector_type(4))) float;
using s16x4 = __attribute__((ext_vector_type(4))) short;
using s16x8 = __attribute__((ext_vector_type(8))) short;
using i32x4 = __attribute__((ext_vector_type(4))) int;

__device__ __forceinline__ short f32_to_bf16_rn(float f) {
  union { float f; uint32_t u; } v; v.f = f;
  uint32_t r = (v.u + 0x7FFFu + ((v.u >> 16) & 1u)) >> 16;  // RTN-even
  return (short)(uint16_t)r;
}

// ---------------- prepass: f32 -> bf16 ----------------
__global__ void __launch_bounds__(256) cvt_x_kernel(const float* __restrict__ in,
                                                    short* __restrict__ out, int n8) {
  int i = blockIdx.x * 256 + threadIdx.x;
  const int stride = gridDim.x * 256;
  for (; i < n8; i += stride) {
    const f32x4* p = (const f32x4*)(in + (size_t)i * 8);
    f32x4 a = p[0];
    f32x4 b = p[1];
    s16x8 o;
#pragma unroll
    for (int j = 0; j < 4; ++j) { o[j] = f32_to_bf16_rn(a[j]); o[j + 4] = f32_to_bf16_rn(b[j]); }
    *(s16x8*)(out + (size_t)i * 8) = o;
  }
}

// ---------------- prepass: int32 (quantized weight) -> bf16 (exact) ----------------
__global__ void __launch_bounds__(256) cvt_w_kernel(const int* __restrict__ in,
                                                    short* __restrict__ out, int n8) {
  int i = blockIdx.x * 256 + threadIdx.x;
  const int stride = gridDim.x * 256;
  for (; i < n8; i += stride) {
    const i32x4* p = (const i32x4*)(in + (size_t)i * 8);
    i32x4 a = p[0];
    i32x4 b = p[1];
    s16x8 o;
#pragma unroll
    for (int j = 0; j < 4; ++j) {
      o[j]     = f32_to_bf16_rn((float)a[j]);
      o[j + 4] = f32_to_bf16_rn((float)b[j]);
    }
    *(s16x8*)(out + (size_t)i * 8) = o;
  }
}

// ---------------- main GEMM (m97 structure): bf16 A [M][K], bf16 W [N][K] (=B^T) ----------------
__global__ void __launch_bounds__(256) gemm_bf16_ws(
    const short* __restrict__ A, const short* __restrict__ Bw,
    const float* __restrict__ scale_p, const float* __restrict__ bias,
    float* __restrict__ out) {
  __shared__ short As[TILE * BK];
  __shared__ short Bs[TILE * BK];

  const int t      = threadIdx.x;
  const int lane   = t & 63;
  const int wave   = t >> 6;
  const int wm     = wave >> 1;   // 2x2 wave grid, each wave owns 64x64
  const int wn     = wave & 1;
  const int lane15   = lane & 15;
  const int laneHalf = lane >> 4;

  // XCD-aware swizzle: nwg = 2048 = 8 * 256 (divisible by 8 -> m157 simple form ok)
  const int bid   = blockIdx.x;
  const int wg    = (bid & 7) * 256 + (bid >> 3);
  const int ntile = wg & 31;    // 32 n-tiles
  const int mtile = wg >> 5;    // 64 m-tiles
  const int m0 = mtile * TILE;
  const int n0 = ntile * TILE;

  f32x4 acc[4][4] = {};

  for (int k0 = 0; k0 < KDIM; k0 += BK) {
    __syncthreads();  // protect LDS from previous iteration's readers
#pragma unroll
    for (int p = 0; p < 4; ++p) {
      // LDS dest must be wave-uniform base + lane*16 (linear); e = element index
      const int e   = p * 2048 + t * 8;
      const int row = e >> 6;      // /64
      const int col = e & 63;
      __builtin_amdgcn_global_load_lds(
          (const __attribute__((address_space(1))) void*)(A + (size_t)(m0 + row) * KDIM + (k0 + col)),
          (__attribute__((address_space(3))) void*)(As + e), 16, 0, 0);
      __builtin_amdgcn_global_load_lds(
          (const __attribute__((address_space(1))) void*)(Bw + (size_t)(n0 + row) * KDIM + (k0 + col)),
          (__attribute__((address_space(3))) void*)(Bs + e), 16, 0, 0);
    }
    __syncthreads();  // compiler emits vmcnt(0) drain here -> gload complete

#pragma unroll
    for (int kk = 0; kk < BK; kk += 32) {
      const int kb = kk + laneHalf * 8;   // 8 contiguous K elems per lane
      s16x8 af[4], bf[4];
#pragma unroll
      for (int i = 0; i < 4; ++i) {
        af[i] = *(const s16x8*)&As[(wm * 64 + i * 16 + lane15) * BK + kb];
        bf[i] = *(const s16x8*)&Bs[(wn * 64 + i * 16 + lane15) * BK + kb];
      }
#pragma unroll
      for (int i = 0; i < 4; ++i)
#pragma unroll
        for (int j = 0; j < 4; ++j)
          acc[i][j] = __builtin_amdgcn_mfma_f32_16x16x32_bf16(af[i], bf[j], acc[i][j], 0, 0, 0);
    }
  }

  // Epilogue: D layout col=lane&15, row=(lane>>4)*4+q (m89-verified)
  const float s = scale_p[0];
#pragma unroll
  for (int j = 0; j < 4; ++j) {
    const int col = n0 + wn * 64 + j * 16 + lane15;
    const float bv = bias[col];
#pragma unroll
    for (int i = 0; i < 4; ++i) {
      const int row = m0 + wm * 64 + i * 16 + laneHalf * 4;
#pragma unroll
      for (int q = 0; q < 4; ++q)
        out[(size_t)(row + q) * NDIM + col] = acc[i][j][q] * s + bv;
    }
  }
}

// ---------------- fallback: reg-staging with on-the-fly conversion (if ws too small) ----------------
__global__ void __launch_bounds__(256) gemm_raw(
    const float* __restrict__ X, const int* __restrict__ W,
    const float* __restrict__ scale_p, const float* __restrict__ bias,
    float* __restrict__ out) {
  __shared__ short As[TILE * BK];
  __shared__ short Bs[TILE * BK];

  const int t      = threadIdx.x;
  const int lane   = t & 63;
  const int wave   = t >> 6;
  const int wm     = wave >> 1;
  const int wn     = wave & 1;
  const int lane15   = lane & 15;
  const int laneHalf = lane >> 4;

  const int bid   = blockIdx.x;
  const int wg    = (bid & 7) * 256 + (bid >> 3);
  const int ntile = wg & 31;
  const int mtile = wg >> 5;
  const int m0 = mtile * TILE;
  const int n0 = ntile * TILE;

  f32x4 acc[4][4] = {};

  for (int k0 = 0; k0 < KDIM; k0 += BK) {
    __syncthreads();
#pragma unroll
    for (int r = 0; r < 8; ++r) {
      const int f   = r * 256 + t;       // float4-unit index, 0..2047
      const int row = f >> 4;
      const int c4  = (f & 15) * 4;
      f32x4 v = *(const f32x4*)(X + (size_t)(m0 + row) * KDIM + (k0 + c4));
      s16x4 h;
#pragma unroll
      for (int j = 0; j < 4; ++j) h[j] = f32_to_bf16_rn(v[j]);
      *(s16x4*)&As[row * BK + c4] = h;

      i32x4 wv = *(const i32x4*)(W + (size_t)(n0 + row) * KDIM + (k0 + c4));
      s16x4 hw;
#pragma unroll
      for (int j = 0; j < 4; ++j) hw[j] = f32_to_bf16_rn((float)wv[j]);
      *(s16x4*)&Bs[row * BK + c4] = hw;
    }
    __syncthreads();

#pragma unroll
    for (int kk = 0; kk < BK; kk += 32) {
      const int kb = kk + laneHalf * 8;
      s16x8 af[4], bf[4];
#pragma unroll
      for (int i = 0; i < 4; ++i) {
        af[i] = *(const s16x8*)&As[(wm * 64 + i * 16 + lane15) * BK + kb];
        bf[i] = *(const s16x8*)&Bs[(wn * 64 + i * 16 + lane15) * BK + kb];
      }
#pragma unroll
      for (int i = 0; i < 4; ++i)
#pragma unroll
        for (int j = 0; j < 4; ++j)
          acc[i][j] = __builtin_amdgcn_mfma_f32_16x16x32_bf16(af[i], bf[j], acc[i][j], 0, 0, 0);
    }
  }

  const float s = scale_p[0];
#pragma unroll
  for (int j = 0; j < 4; ++j) {
    const int col = n0 + wn * 64 + j * 16 + lane15;
    const float bv = bias[col];
#pragma unroll
    for (int i = 0; i < 4; ++i) {
      const int row = m0 + wm * 64 + i * 16 + laneHalf * 4;
#pragma unroll
      for (int q = 0; q < 4; ++q)
        out[(size_t)(row + q) * NDIM + col] = acc[i][j][q] * s + bv;
    }
  }
}

extern "C" void kernel_launch(void* const* d_in, const int* in_sizes, int n_in,
                              void* d_out, int out_size, void* d_ws, size_t ws_size,
                              hipStream_t stream) {
  const float* x     = (const float*)d_in[0];
  const int*   w     = (const int*)d_in[1];    // integer inputs materialize as int32
  const float* scale = (const float*)d_in[2];
  const float* bias  = (const float*)d_in[3];
  float* out = (float*)d_out;

  const size_t a_elems = (size_t)MDIM * KDIM;  // 33,554,432
  const size_t b_elems = (size_t)NDIM * KDIM;  // 16,777,216
  const size_t need    = (a_elems + b_elems) * sizeof(short);  // 100,663,296 B

  const int nwg = (MDIM / TILE) * (NDIM / TILE);  // 64*32 = 2048

  if (ws_size >= need) {
    short* Abf = (short*)d_ws;
    short* Wbf = Abf + a_elems;
    cvt_x_kernel<<<2048, 256, 0, stream>>>(x, Abf, (int)(a_elems / 8));
    cvt_w_kernel<<<2048, 256, 0, stream>>>(w, Wbf, (int)(b_elems / 8));
    gemm_bf16_ws<<<nwg, 256, 0, stream>>>(Abf, Wbf, scale, bias, out);
  } else {
    gemm_raw<<<nwg, 256, 0, stream>>>(x, w, scale, bias, out);
  }
}

// Round 3
// 288.950 us; speedup vs baseline: 1.5378x; 1.5378x over previous
//
#include <hip/hip_runtime.h>
#include <stdint.h>
#include <stddef.h>

// Problem geometry (B=4, S=2048, DIN=4096, DOUT=4096)
constexpr int MDIM = 8192;   // B*S
constexpr int NDIM = 4096;   // DOUT
constexpr int KDIM = 4096;   // DIN

using f32x4 = __attribute__((ext_vector_type(4))) float;
using s16x4 = __attribute__((ext_vector_type(4))) short;
using s16x8 = __attribute__((ext_vector_type(8))) short;
using i32x4 = __attribute__((ext_vector_type(4))) int;

__device__ __forceinline__ short f32_to_bf16_rn(float f) {
  union { float f; uint32_t u; } v; v.f = f;
  uint32_t r = (v.u + 0x7FFFu + ((v.u >> 16) & 1u)) >> 16;  // RTN-even
  return (short)(uint16_t)r;
}

// ---------------- prepass: f32 -> bf16 ----------------
__global__ void __launch_bounds__(256) cvt_x_kernel(const float* __restrict__ in,
                                                    short* __restrict__ out, int n8) {
  int i = blockIdx.x * 256 + threadIdx.x;
  const int stride = gridDim.x * 256;
  for (; i < n8; i += stride) {
    const f32x4* p = (const f32x4*)(in + (size_t)i * 8);
    f32x4 a = p[0];
    f32x4 b = p[1];
    s16x8 o;
#pragma unroll
    for (int j = 0; j < 4; ++j) { o[j] = f32_to_bf16_rn(a[j]); o[j + 4] = f32_to_bf16_rn(b[j]); }
    *(s16x8*)(out + (size_t)i * 8) = o;
  }
}

// ---------------- prepass: int32 (quantized weight) -> bf16 (exact) ----------------
__global__ void __launch_bounds__(256) cvt_w_kernel(const int* __restrict__ in,
                                                    short* __restrict__ out, int n8) {
  int i = blockIdx.x * 256 + threadIdx.x;
  const int stride = gridDim.x * 256;
  for (; i < n8; i += stride) {
    const i32x4* p = (const i32x4*)(in + (size_t)i * 8);
    i32x4 a = p[0];
    i32x4 b = p[1];
    s16x8 o;
#pragma unroll
    for (int j = 0; j < 4; ++j) {
      o[j]     = f32_to_bf16_rn((float)a[j]);
      o[j + 4] = f32_to_bf16_rn((float)b[j]);
    }
    *(s16x8*)(out + (size_t)i * 8) = o;
  }
}

// =====================================================================
// 256x256 8-phase GEMM (m201 template, plain HIP):
//   A [M][K] bf16, Bw [N][K] bf16 (= B^T), C = A*Bw^T * scale + bias
// LDS layout per matrix per buffer (32 KiB): subtiled
//   [st_c(=ks) 0..1][st_r 0..15][ir 0..15][icb 0..63 bytes]
//   with XOR swizzle: phys = lin ^ (((lin>>9)&1)<<5)   (st_16x32)
// Staged via global_load_lds (linear dest) from inverse-swizzled source.
// Half-tile stream order per K-tile: [B-ks0, A-ks0, B-ks1, A-ks1].
// =====================================================================

#define BAR asm volatile("s_barrier" ::: "memory")
#define WAITVM6 asm volatile("s_waitcnt vmcnt(6)" ::: "memory")
#define WAITVM0 asm volatile("s_waitcnt vmcnt(0)" ::: "memory")

#define GLL(src, dst) __builtin_amdgcn_global_load_lds(                     \
    (const __attribute__((address_space(1))) void*)(src),                   \
    (__attribute__((address_space(3))) void*)(dst), 16, 0, 0)

// grow: const char* global row base (matrix + tile_row0*KDIM), row stride 8192 B
// ldsmat: 0 (A) or 65536 (B)
#define STAGE(grow, ldsmat, ks, tau) do {                                   \
  const int buf_ = (tau) & 1;                                               \
  GLL((grow) + (size_t)r0 * 8192 + (size_t)(tau) * 128 + (ks) * 64 + cb,    \
      lds + (ldsmat) + buf_ * 32768 + (ks) * 16384 + t * 16);               \
  GLL((grow) + (size_t)r1 * 8192 + (size_t)(tau) * 128 + (ks) * 64 + cb,    \
      lds + (ldsmat) + buf_ * 32768 + (ks) * 16384 + 8192 + t * 16);        \
} while (0)

#define LDA(cur, ks, i) (*(const s16x8*)(lds + (cur) * 32768 + (ks) * 16384 \
    + (wm * 8 + (i)) * 1024 + laneoff))
#define LDB(cur, ks, j) (*(const s16x8*)(lds + 65536 + (cur) * 32768        \
    + (ks) * 16384 + (wn * 4 + (j)) * 1024 + laneoff))

#define READ_B(cur, ks) do {                                                \
  _Pragma("unroll") for (int j = 0; j < 4; ++j) bf[j] = LDB(cur, ks, j);    \
} while (0)
#define READ_A(cur, ks, ibase) do {                                         \
  _Pragma("unroll") for (int i = 0; i < 4; ++i) af[i] = LDA(cur, ks, (ibase) + i); \
} while (0)

#define MFMA16(ibase) do {                                                  \
  __builtin_amdgcn_s_setprio(1);                                            \
  _Pragma("unroll") for (int i = 0; i < 4; ++i)                             \
  _Pragma("unroll") for (int j = 0; j < 4; ++j)                             \
    acc[(ibase) + i][j] = __builtin_amdgcn_mfma_f32_16x16x32_bf16(          \
        af[i], bf[j], acc[(ibase) + i][j], 0, 0, 0);                        \
  __builtin_amdgcn_s_setprio(0);                                            \
} while (0)

// One K-tile = 4 phases. nstage: 4=full stream, 1=only ph1 stage, 0=none.
// endvm: 6 -> vmcnt(6), 0 -> vmcnt(0), -1 -> none.
#define KTILE(t_, cur, nstage, endvm) do {                                  \
  /* ph1: ks0, frags 0-3 */                                                 \
  READ_B(cur, 0); READ_A(cur, 0, 0);                                        \
  if ((nstage) >= 1) STAGE(Arow, 0, 1, (t_) + 1);        /* t+1 q3: A-ks1 */\
  BAR; MFMA16(0); BAR;                                                      \
  /* ph2: ks0, frags 4-7 (reuse bf) */                                      \
  READ_A(cur, 0, 4);                                                        \
  if ((nstage) == 4) STAGE(Brow, 65536, 0, (t_) + 2);    /* t+2 q0: B-ks0 */\
  BAR; MFMA16(4); BAR;                                                      \
  /* ph3: ks1, frags 0-3 */                                                 \
  READ_B(cur, 1); READ_A(cur, 1, 0);                                        \
  if ((nstage) == 4) STAGE(Arow, 0, 0, (t_) + 2);        /* t+2 q1: A-ks0 */\
  BAR; MFMA16(0); BAR;                                                      \
  /* ph4: ks1, frags 4-7 */                                                 \
  READ_A(cur, 1, 4);                                                        \
  if ((nstage) == 4) STAGE(Brow, 65536, 1, (t_) + 2);    /* t+2 q2: B-ks1 */\
  BAR; MFMA16(4);                                                           \
  if ((endvm) == 6) { WAITVM6; } else if ((endvm) == 0) { WAITVM0; }        \
  BAR;                                                                      \
} while (0)

__global__ void __launch_bounds__(512, 2) gemm_bf16_8phase(
    const short* __restrict__ A, const short* __restrict__ Bw,
    const float* __restrict__ scale_p, const float* __restrict__ bias,
    float* __restrict__ out) {
  __shared__ __align__(16) char lds[131072];

  const int t      = threadIdx.x;        // 0..511
  const int lane   = t & 63;
  const int wave   = t >> 6;
  const int wm     = wave >> 2;          // 0..1  (row half: 128 rows)
  const int wn     = wave & 3;           // 0..3  (col quarter: 64 cols)
  const int lane15 = lane & 15;
  const int lh     = lane >> 4;          // 0..3

  // swizzled read offset within a [st_r][16][64B] region.
  // FIX (round 2 -> 3): swizzle is XOR of byte-bit-5, and lh*16 already
  // occupies bit 5 -- '+' carried into bit 6 for lane15>=8 && lh>=2,
  // reading wrong rows / past the region (NaN). Must be '^'.
  const int laneoff = (lane15 * 64 + lh * 16) ^ ((lane15 & 8) << 2);

  // stage decode: LDS slot o = l*8192 + t*16 (+ks*16384) holds element at
  // a = o ^ (((o>>9)&1)<<5); here bit9 of o depends only on t.
  const int ax = ((t >> 5) & 1) << 5;
  const int a0 = (t * 16) ^ ax;
  const int a1 = (8192 + t * 16) ^ ax;
  const int r0 = (((a0 >> 10) & 15) << 4) | ((a0 >> 6) & 15);
  const int r1 = (((a1 >> 10) & 15) << 4) | ((a1 >> 6) & 15);
  const int cb = a0 & 63;                // col byte within 64B row (same for l=0,1)

  // XCD-aware swizzle: nwg = 512 (divisible by 8)
  const int bid   = blockIdx.x;
  const int wg    = (bid & 7) * 64 + (bid >> 3);
  const int ntile = wg & 15;             // 16 n-tiles
  const int mtile = wg >> 4;             // 32 m-tiles
  const int m0 = mtile * 256;
  const int n0 = ntile * 256;

  const char* Arow = (const char*)(A + (size_t)m0 * KDIM);
  const char* Brow = (const char*)(Bw + (size_t)n0 * KDIM);

  f32x4 acc[8][4] = {};
  s16x8 af[4], bf[4];

  // Prologue: tile0 (q0..q3) -> buf0, tile1 (q0..q2) -> buf1; 14 loads/wave.
  STAGE(Brow, 65536, 0, 0);
  STAGE(Arow, 0,     0, 0);
  STAGE(Brow, 65536, 1, 0);
  STAGE(Arow, 0,     1, 0);
  STAGE(Brow, 65536, 0, 1);
  STAGE(Arow, 0,     0, 1);
  STAGE(Brow, 65536, 1, 1);
  WAITVM6;   // tile0 fully landed; 3 half-tiles of tile1 in flight
  BAR;

  // Main: 64 K-tiles total; pairs keep buf index compile-time.
#pragma unroll 1
  for (int tp = 0; tp < 31; ++tp) {
    const int t2 = tp * 2;
    KTILE(t2,     0, 4, 6);
    KTILE(t2 + 1, 1, 4, 6);
  }
  KTILE(62, 0, 1, 0);    // issues last half (tile63 q3), then drain
  KTILE(63, 1, 0, -1);

  // Epilogue: D layout col=lane&15, row=(lane>>4)*4+q (m89-verified)
  const float s = scale_p[0];
#pragma unroll
  for (int j = 0; j < 4; ++j) {
    const int col = n0 + wn * 64 + j * 16 + lane15;
    const float bv = bias[col];
#pragma unroll
    for (int i = 0; i < 8; ++i) {
      const int row = m0 + wm * 128 + i * 16 + lh * 4;
#pragma unroll
      for (int q = 0; q < 4; ++q)
        out[(size_t)(row + q) * NDIM + col] = acc[i][j][q] * s + bv;
    }
  }
}

// ---------------- fallback: m97-style reg-staging with on-the-fly conversion ----------------
constexpr int FTILE = 128;
constexpr int FBK   = 64;

__global__ void __launch_bounds__(256) gemm_raw(
    const float* __restrict__ X, const int* __restrict__ W,
    const float* __restrict__ scale_p, const float* __restrict__ bias,
    float* __restrict__ out) {
  __shared__ short As[FTILE * FBK];
  __shared__ short Bs[FTILE * FBK];

  const int t      = threadIdx.x;
  const int lane   = t & 63;
  const int wave   = t >> 6;
  const int wm     = wave >> 1;
  const int wn     = wave & 1;
  const int lane15   = lane & 15;
  const int laneHalf = lane >> 4;

  const int bid   = blockIdx.x;
  const int wg    = (bid & 7) * 256 + (bid >> 3);
  const int ntile = wg & 31;
  const int mtile = wg >> 5;
  const int m0 = mtile * FTILE;
  const int n0 = ntile * FTILE;

  f32x4 acc[4][4] = {};

  for (int k0 = 0; k0 < KDIM; k0 += FBK) {
    __syncthreads();
#pragma unroll
    for (int r = 0; r < 8; ++r) {
      const int f   = r * 256 + t;
      const int row = f >> 4;
      const int c4  = (f & 15) * 4;
      f32x4 v = *(const f32x4*)(X + (size_t)(m0 + row) * KDIM + (k0 + c4));
      s16x4 h;
#pragma unroll
      for (int j = 0; j < 4; ++j) h[j] = f32_to_bf16_rn(v[j]);
      *(s16x4*)&As[row * FBK + c4] = h;

      i32x4 wv = *(const i32x4*)(W + (size_t)(n0 + row) * FBK * 64 / FBK / 64 * KDIM + (k0 + c4));
      s16x4 hw;
#pragma unroll
      for (int j = 0; j < 4; ++j) hw[j] = f32_to_bf16_rn((float)wv[j]);
      *(s16x4*)&Bs[row * FBK + c4] = hw;
    }
    __syncthreads();

#pragma unroll
    for (int kk = 0; kk < FBK; kk += 32) {
      const int kb = kk + laneHalf * 8;
      s16x8 af[4], bf[4];
#pragma unroll
      for (int i = 0; i < 4; ++i) {
        af[i] = *(const s16x8*)&As[(wm * 64 + i * 16 + lane15) * FBK + kb];
        bf[i] = *(const s16x8*)&Bs[(wn * 64 + i * 16 + lane15) * FBK + kb];
      }
#pragma unroll
      for (int i = 0; i < 4; ++i)
#pragma unroll
        for (int j = 0; j < 4; ++j)
          acc[i][j] = __builtin_amdgcn_mfma_f32_16x16x32_bf16(af[i], bf[j], acc[i][j], 0, 0, 0);
    }
  }

  const float s = scale_p[0];
#pragma unroll
  for (int j = 0; j < 4; ++j) {
    const int col = n0 + wn * 64 + j * 16 + lane15;
    const float bv = bias[col];
#pragma unroll
    for (int i = 0; i < 4; ++i) {
      const int row = m0 + wm * 64 + i * 16 + laneHalf * 4;
#pragma unroll
      for (int q = 0; q < 4; ++q)
        out[(size_t)(row + q) * NDIM + col] = acc[i][j][q] * s + bv;
    }
  }
}

extern "C" void kernel_launch(void* const* d_in, const int* in_sizes, int n_in,
                              void* d_out, int out_size, void* d_ws, size_t ws_size,
                              hipStream_t stream) {
  const float* x     = (const float*)d_in[0];
  const int*   w     = (const int*)d_in[1];    // integer inputs materialize as int32
  const float* scale = (const float*)d_in[2];
  const float* bias  = (const float*)d_in[3];
  float* out = (float*)d_out;

  const size_t a_elems = (size_t)MDIM * KDIM;  // 33,554,432
  const size_t b_elems = (size_t)NDIM * KDIM;  // 16,777,216
  const size_t need    = (a_elems + b_elems) * sizeof(short);  // 100,663,296 B

  if (ws_size >= need) {
    short* Abf = (short*)d_ws;
    short* Wbf = Abf + a_elems;
    cvt_x_kernel<<<2048, 256, 0, stream>>>(x, Abf, (int)(a_elems / 8));
    cvt_w_kernel<<<2048, 256, 0, stream>>>(w, Wbf, (int)(b_elems / 8));
    const int nwg = (MDIM / 256) * (NDIM / 256);  // 32*16 = 512
    gemm_bf16_8phase<<<nwg, 512, 0, stream>>>(Abf, Wbf, scale, bias, out);
  } else {
    const int nwg = (MDIM / FTILE) * (NDIM / FTILE);  // 2048
    gemm_raw<<<nwg, 256, 0, stream>>>(x, w, scale, bias, out);
  }
}